// Round 9
// baseline (141.449 us; speedup 1.0000x reference)
//
#include <hip/hip_runtime.h>

#define TSEQ 2048
#define NHEAD 16
#define HD 64
#define CDIM 1024
#define BT 4096  // B*T

typedef unsigned short u16;
typedef __bf16 bf16x8 __attribute__((ext_vector_type(8)));
typedef float f32x4 __attribute__((ext_vector_type(4)));
typedef float f32x16 __attribute__((ext_vector_type(16)));

union Frag {
  int4 i4;
  bf16x8 b;
  u16 u[8];
};

__device__ __forceinline__ u16 f2b(float f) {
  union { float f; unsigned u; } x;
  x.f = f;
  unsigned r = x.u + 0x7fffu + ((x.u >> 16) & 1u);
  return (u16)(r >> 16);
}

// ---------------- fp32 -> bf16 convert (all three inputs, one launch) ----------------
#define N4X 1048576   // x: 4194304 f32
#define N4W1 786432   // Wkqv: 3145728
#define N4W2 262144   // Wproj: 1048576
__global__ void cvt3_kernel(const float* __restrict__ x, const float* __restrict__ w1,
                            const float* __restrict__ w2, u16* __restrict__ ox,
                            u16* __restrict__ o1, u16* __restrict__ o2) {
  int i = blockIdx.x * blockDim.x + threadIdx.x;
  int stride = gridDim.x * blockDim.x;
  for (int idx = i; idx < N4X + N4W1 + N4W2; idx += stride) {
    const float4* src;
    ushort4* dst;
    int k;
    if (idx < N4X) { src = (const float4*)x; dst = (ushort4*)ox; k = idx; }
    else if (idx < N4X + N4W1) { src = (const float4*)w1; dst = (ushort4*)o1; k = idx - N4X; }
    else { src = (const float4*)w2; dst = (ushort4*)o2; k = idx - N4X - N4W1; }
    float4 f = src[k];
    ushort4 o;
    o.x = f2b(f.x); o.y = f2b(f.y); o.z = f2b(f.z); o.w = f2b(f.w);
    dst[k] = o;
  }
}

// ---------------- shared GEMM mainloop (C = A * Bw^T), 128x128 tile ----------------
__device__ __forceinline__ void gload_lds16(const u16* g, u16* l) {
  __builtin_amdgcn_global_load_lds((__attribute__((address_space(1))) void*)g,
                                   (__attribute__((address_space(3))) void*)l, 16, 0, 0);
}

__device__ __forceinline__ void gemm_tiles(const u16* __restrict__ A, const u16* __restrict__ Bw,
                                           int K, int m0, int n0, u16* Ash, u16* Bsh,
                                           f32x4 acc[4][4]) {
  const int tid = threadIdx.x;
  const int lane = tid & 63;
  const int w = tid >> 6;
  const int wr = (w >> 1) * 64, wc = (w & 1) * 64;
  const int lr = lane & 15;
  const int lkb = (lane >> 4) << 3;
  const int r0 = tid >> 2;         // 0..63
  const int c0 = (tid & 3) << 3;   // 0,8,16,24

  for (int k0 = 0; k0 < K; k0 += 32) {
#pragma unroll
    for (int s = 0; s < 2; s++) {
      gload_lds16(&A[(size_t)(m0 + s * 64 + r0) * K + k0 + c0], &Ash[(s * 256 + tid) * 8]);
      gload_lds16(&Bw[(size_t)(n0 + s * 64 + r0) * K + k0 + c0], &Bsh[(s * 256 + tid) * 8]);
    }
    __syncthreads();
    Frag af[4], bfr[4];
#pragma unroll
    for (int i = 0; i < 4; i++) {
      af[i].i4 = *(const int4*)&Ash[(wr + i * 16 + lr) * 32 + lkb];
      bfr[i].i4 = *(const int4*)&Bsh[(wc + i * 16 + lr) * 32 + lkb];
    }
#pragma unroll
    for (int mf = 0; mf < 4; mf++)
#pragma unroll
      for (int nf = 0; nf < 4; nf++)
        acc[mf][nf] = __builtin_amdgcn_mfma_f32_16x16x32_bf16(af[mf].b, bfr[nf].b, acc[mf][nf], 0, 0, 0);
    __syncthreads();
  }
}

// ---------------- GEMM1: kqv = x @ Wkqv^T + b ----------------
// q/k scattered to [bh][t][d]; v^T to [bh][d][c] where c = t with BITS 2<->3 of
// (t&63) swapped — so attention's permuted-kv PV contraction reads contiguous 16B.
__global__ __launch_bounds__(256) void gemm_kqv(const u16* __restrict__ xb, const u16* __restrict__ wb,
                                                const float* __restrict__ bias,
                                                u16* __restrict__ qb, u16* __restrict__ kb,
                                                u16* __restrict__ vtb) {
  __shared__ u16 Ash[128 * 32];
  __shared__ u16 Bsh[128 * 32];
  const int m0 = blockIdx.y * 128, n0 = blockIdx.x * 128;
  f32x4 acc[4][4];
#pragma unroll
  for (int i = 0; i < 4; i++)
#pragma unroll
    for (int j = 0; j < 4; j++) acc[i][j] = (f32x4){0.f, 0.f, 0.f, 0.f};

  gemm_tiles(xb, wb, CDIM, m0, n0, Ash, Bsh, acc);

  const int tid = threadIdx.x;
  const int lane = tid & 63;
  const int w = tid >> 6;
  const int wr = (w >> 1) * 64, wc = (w & 1) * 64;
  const int lr = lane & 15;
  const int rbase = (lane >> 4) << 2;
#pragma unroll
  for (int mf = 0; mf < 4; mf++) {
#pragma unroll
    for (int nf = 0; nf < 4; nf++) {
      f32x4 a = acc[mf][nf];
      int n = n0 + wc + nf * 16 + lr;
      float bval = bias[n];
      int h = n / 192;
      int rem = n - h * 192;
      int s = rem >> 6;
      int d = rem & 63;
      float scale = (s == 1) ? 0.125f : 1.f;  // fold 1/sqrt(64) into q
      u16* dst = (s == 0) ? kb : qb;
#pragma unroll
      for (int r = 0; r < 4; r++) {
        int m = m0 + wr + mf * 16 + rbase + r;
        int bb = m >> 11, tt = m & 2047;
        int bh = (bb << 4) + h;
        u16 val = f2b((a[r] + bval) * scale);
        if (s == 2) {
          int t63 = tt & 63;
          int c = (t63 & 51) | ((t63 & 8) >> 1) | ((t63 & 4) << 1);  // swap bits 2,3
          vtb[((size_t)bh * HD + d) * TSEQ + (tt & ~63) + c] = val;
        } else {
          dst[((size_t)bh * TSEQ + tt) * HD + d] = val;
        }
      }
    }
  }
}

// ---------------- GEMM2: out = y @ Wproj^T + b (fp32 out) ----------------
__global__ __launch_bounds__(256) void gemm_proj(const u16* __restrict__ yb, const u16* __restrict__ wb,
                                                 const float* __restrict__ bias,
                                                 float* __restrict__ out) {
  __shared__ u16 Ash[128 * 32];
  __shared__ u16 Bsh[128 * 32];
  const int m0 = blockIdx.y * 128, n0 = blockIdx.x * 128;
  f32x4 acc[4][4];
#pragma unroll
  for (int i = 0; i < 4; i++)
#pragma unroll
    for (int j = 0; j < 4; j++) acc[i][j] = (f32x4){0.f, 0.f, 0.f, 0.f};

  gemm_tiles(yb, wb, CDIM, m0, n0, Ash, Bsh, acc);

  const int tid = threadIdx.x;
  const int lane = tid & 63;
  const int w = tid >> 6;
  const int wr = (w >> 1) * 64, wc = (w & 1) * 64;
  const int lr = lane & 15;
  const int rbase = (lane >> 4) << 2;
#pragma unroll
  for (int mf = 0; mf < 4; mf++) {
#pragma unroll
    for (int nf = 0; nf < 4; nf++) {
      f32x4 a = acc[mf][nf];
      int n = n0 + wc + nf * 16 + lr;
      float bval = bias[n];
#pragma unroll
      for (int r = 0; r < 4; r++) {
        int m = m0 + wr + mf * 16 + rbase + r;
        out[(size_t)m * CDIM + n] = a[r] + bval;
      }
    }
  }
}

// ---------------- causal flash attention v9: split-KV + manual 2-bank pipeline ----
// r8 structure (2048 blocks x 128 thr; block = (bh, 32-row strip); 2 waves split
// KV tiles even/odd; fixed-shift softmax additive merge) PLUS an explicit
// software pipeline: tile j+2's K/V fragments are loaded into the OTHER register
// bank before tile j's compute, sched_barrier(0) pins the issue point. The
// compiler's counted vmcnt then overlaps ~300-600cy of L2 latency with tile j's
// MFMA+exp+pack (~500cy). This is what the backend refused to do on its own
// (r8: VGPR=60, zero lookahead, 70us at 36% occupancy).
__global__ __launch_bounds__(128, 3) void attn_kernel(const u16* __restrict__ qb,
                                                      const u16* __restrict__ kb,
                                                      const u16* __restrict__ vtb,
                                                      u16* __restrict__ yb) {
  __shared__ float Osh[64][33];  // wave-1 partial O (padded: conflict-free)
  __shared__ float lsh[64];      // wave-1 partial row sums

  const int tid = threadIdx.x;
  const int lane = tid & 63;
  const int w = tid >> 6;          // 0..1 (KV-parity owner)
  const int l31 = lane & 31;
  const int hi32 = lane >> 5;

  // job decode: bh = jj&31; class r = jj>>5 -> strip s via perm so each stride-256
  // CU group's 8 classes get s = {63-c,48+c,47-c,32+c,31-c,16+c,15-c,c} (sum 252);
  // heavy strips dispatched first.
  const int jj = blockIdx.x;
  const int bh = jj & 31;
  const int r = jj >> 5;
  const int g = r & 7, sel = r >> 3;
  int s;
  switch (sel) {
    case 0: s = 63 - g; break;
    case 1: s = 48 + g; break;
    case 2: s = 47 - g; break;
    case 3: s = 32 + g; break;
    case 4: s = 31 - g; break;
    case 5: s = 16 + g; break;
    case 6: s = 15 - g; break;
    default: s = g; break;
  }
  const int q0w = s * 32;
  const int nt32 = s + 1;          // 32-wide KV tiles
  const int qg = q0w + l31;        // this lane's q row

  const u16* Qp = qb + (size_t)bh * TSEQ * HD;
  const u16* Kp = kb + (size_t)bh * TSEQ * HD;
  const u16* Vt = vtb + (size_t)bh * HD * TSEQ;

  // Q B-frags (4 d-steps of 16) in registers for the whole job
  Frag qf[4];
#pragma unroll
  for (int k = 0; k < 4; k++)
    qf[k].i4 = *(const int4*)&Qp[(size_t)(q0w + l31) * HD + k * 16 + hi32 * 8];

  f32x16 O0, O1;
  float lp = 0.f;
#pragma unroll
  for (int i = 0; i < 16; i++) { O0[i] = 0.f; O1[i] = 0.f; }

#define LOADKV(KA, V0, V1, J)                                                        \
  {                                                                                  \
    const int kv0_ = (J) * 32;                                                       \
    _Pragma("unroll")                                                                \
    for (int k = 0; k < 4; k++)                                                      \
      KA[k].i4 = *(const int4*)&Kp[(size_t)(kv0_ + l31) * HD + k * 16 + hi32 * 8];   \
    _Pragma("unroll")                                                                \
    for (int k = 0; k < 2; k++) {                                                    \
      V0[k].i4 = *(const int4*)&Vt[(size_t)l31 * TSEQ + kv0_ + (k * 2 + hi32) * 8];  \
      V1[k].i4 = *(const int4*)&Vt[(size_t)(32 + l31) * TSEQ + kv0_ + (k * 2 + hi32) * 8]; \
    }                                                                                \
  }

#define PACK(dst, SV, base)                                                          \
    asm("v_cvt_pk_bf16_f32 %0, %1, %2" : "=v"(dst.i4.x) : "v"(SV[base + 0]), "v"(SV[base + 1])); \
    asm("v_cvt_pk_bf16_f32 %0, %1, %2" : "=v"(dst.i4.y) : "v"(SV[base + 2]), "v"(SV[base + 3])); \
    asm("v_cvt_pk_bf16_f32 %0, %1, %2" : "=v"(dst.i4.z) : "v"(SV[base + 4]), "v"(SV[base + 5])); \
    asm("v_cvt_pk_bf16_f32 %0, %1, %2" : "=v"(dst.i4.w) : "v"(SV[base + 6]), "v"(SV[base + 7]));

#define COMPUTE(KA, V0, V1, J)                                                       \
  {                                                                                  \
    f32x16 S0;                                                                       \
    _Pragma("unroll") for (int i = 0; i < 16; i++) S0[i] = 0.f;                      \
    __builtin_amdgcn_s_setprio(1);                                                   \
    _Pragma("unroll") for (int k = 0; k < 4; k++)                                    \
      S0 = __builtin_amdgcn_mfma_f32_32x32x16_bf16(KA[k].b, qf[k].b, S0, 0, 0, 0);   \
    __builtin_amdgcn_s_setprio(0);                                                   \
    if ((J) == nt32 - 1) {                                                           \
      const int kv0_ = (J) * 32;                                                     \
      _Pragma("unroll") for (int reg = 0; reg < 16; reg++) {                         \
        int crow = (reg & 3) + 8 * (reg >> 2) + 4 * hi32;                            \
        S0[reg] = (kv0_ + crow <= qg) ? __expf(S0[reg]) : 0.f;                       \
      }                                                                              \
    } else {                                                                         \
      _Pragma("unroll") for (int reg = 0; reg < 16; reg++) S0[reg] = __expf(S0[reg]); \
    }                                                                                \
    _Pragma("unroll") for (int reg = 0; reg < 16; reg++) lp += S0[reg];              \
    Frag pa[2];                                                                      \
    PACK(pa[0], S0, 0)                                                               \
    PACK(pa[1], S0, 8)                                                               \
    __builtin_amdgcn_s_setprio(1);                                                   \
    _Pragma("unroll") for (int k = 0; k < 2; k++) {                                  \
      O0 = __builtin_amdgcn_mfma_f32_32x32x16_bf16(pa[k].b, V0[k].b, O0, 0, 0, 0);   \
      O1 = __builtin_amdgcn_mfma_f32_32x32x16_bf16(pa[k].b, V1[k].b, O1, 0, 0, 0);   \
    }                                                                                \
    __builtin_amdgcn_s_setprio(0);                                                   \
  }

  // manual 2-bank software pipeline over tiles j = w, w+2, ...
  Frag kaA[4], v0A[2], v1A[2], kaB[4], v0B[2], v1B[2];
  int j = w;
  if (j < nt32) LOADKV(kaA, v0A, v1A, j);
  while (j < nt32) {
    if (j + 2 < nt32) LOADKV(kaB, v0B, v1B, j + 2);
    __builtin_amdgcn_sched_barrier(0);  // keep prefetch issue ABOVE the compute
    COMPUTE(kaA, v0A, v1A, j);
    j += 2;
    if (j >= nt32) break;
    if (j + 2 < nt32) LOADKV(kaA, v0A, v1A, j + 2);
    __builtin_amdgcn_sched_barrier(0);
    COMPUTE(kaB, v0B, v1B, j);
    j += 2;
  }
#undef LOADKV
#undef PACK
#undef COMPUTE

  // intra-wave k-half reduce (lane^32 partner covers the other kv offsets)
  float lpw = lp + __shfl_xor(lp, 32);

  // cross-wave merge: additive (fixed-shift) -> one LDS round trip
  if (w == 1) {
#pragma unroll
    for (int reg = 0; reg < 16; reg++) {
      Osh[lane][reg] = O0[reg];
      Osh[lane][16 + reg] = O1[reg];
    }
    lsh[lane] = lpw;
  }
  __syncthreads();
  if (w == 0) {
#pragma unroll
    for (int reg = 0; reg < 16; reg++) {
      O0[reg] += Osh[lane][reg];
      O1[reg] += Osh[lane][16 + reg];
    }
    float ltot = lpw + lsh[lane];
    const int b = bh >> 4, h = bh & 15;
#pragma unroll
    for (int reg = 0; reg < 16; reg++) {
      int qlocal = (reg & 3) + 8 * (reg >> 2) + 4 * hi32;
      float invr = 1.f / __shfl(ltot, qlocal);
      int t = q0w + qlocal;
      size_t rowoff = ((size_t)(b * TSEQ + t) << 10) + (h << 6);
      yb[rowoff + l31] = f2b(O0[reg] * invr);
      yb[rowoff + 32 + l31] = f2b(O1[reg] * invr);
    }
  }
}

extern "C" void kernel_launch(void* const* d_in, const int* in_sizes, int n_in,
                              void* d_out, int out_size, void* d_ws, size_t ws_size,
                              hipStream_t stream) {
  const float* x = (const float*)d_in[0];
  const float* Wkqv = (const float*)d_in[1];
  const float* bkqv = (const float*)d_in[2];
  const float* Wproj = (const float*)d_in[3];
  const float* bproj = (const float*)d_in[4];
  float* out = (float*)d_out;

  u16* ws = (u16*)d_ws;
  u16* xb = ws;                       // 4194304
  u16* wkqvb = xb + 4194304;          // 3145728
  u16* wprojb = wkqvb + 3145728;      // 1048576
  u16* qb = wprojb + 1048576;         // 4194304
  u16* kb = qb + 4194304;             // 4194304
  u16* vtb = kb + 4194304;            // 4194304 ([bh][d][t], cols bit-2/3 swapped per 64)
  u16* yb = vtb + 4194304;            // 4194304  (total 48 MB)

  cvt3_kernel<<<2048, 256, 0, stream>>>(x, Wkqv, Wproj, xb, wkqvb, wprojb);
  gemm_kqv<<<dim3(24, 32), 256, 0, stream>>>(xb, wkqvb, bkqv, qb, kb, vtb);
  attn_kernel<<<2048, 128, 0, stream>>>(qb, kb, vtb, yb);
  gemm_proj<<<dim3(8, 32), 256, 0, stream>>>(yb, wprojb, bproj, out);
}

// Round 10
// 108.892 us; speedup vs baseline: 1.2990x; 1.2990x over previous
//
#include <hip/hip_runtime.h>

#define TSEQ 2048
#define NHEAD 16
#define HD 64
#define CDIM 1024
#define BT 4096  // B*T

typedef unsigned short u16;
typedef __bf16 bf16x8 __attribute__((ext_vector_type(8)));
typedef float f32x4 __attribute__((ext_vector_type(4)));
typedef float f32x16 __attribute__((ext_vector_type(16)));

union Frag {
  int4 i4;
  bf16x8 b;
  u16 u[8];
};

__device__ __forceinline__ u16 f2b(float f) {
  union { float f; unsigned u; } x;
  x.f = f;
  unsigned r = x.u + 0x7fffu + ((x.u >> 16) & 1u);
  return (u16)(r >> 16);
}

// ---------------- fp32 -> bf16 convert (all three inputs, one launch) ----------------
#define N4X 1048576   // x: 4194304 f32
#define N4W1 786432   // Wkqv: 3145728
#define N4W2 262144   // Wproj: 1048576
__global__ void cvt3_kernel(const float* __restrict__ x, const float* __restrict__ w1,
                            const float* __restrict__ w2, u16* __restrict__ ox,
                            u16* __restrict__ o1, u16* __restrict__ o2) {
  int i = blockIdx.x * blockDim.x + threadIdx.x;
  int stride = gridDim.x * blockDim.x;
  for (int idx = i; idx < N4X + N4W1 + N4W2; idx += stride) {
    const float4* src;
    ushort4* dst;
    int k;
    if (idx < N4X) { src = (const float4*)x; dst = (ushort4*)ox; k = idx; }
    else if (idx < N4X + N4W1) { src = (const float4*)w1; dst = (ushort4*)o1; k = idx - N4X; }
    else { src = (const float4*)w2; dst = (ushort4*)o2; k = idx - N4X - N4W1; }
    float4 f = src[k];
    ushort4 o;
    o.x = f2b(f.x); o.y = f2b(f.y); o.z = f2b(f.z); o.w = f2b(f.w);
    dst[k] = o;
  }
}

// ---------------- shared GEMM mainloop (C = A * Bw^T), 128x128 tile ----------------
__device__ __forceinline__ void gload_lds16(const u16* g, u16* l) {
  __builtin_amdgcn_global_load_lds((__attribute__((address_space(1))) void*)g,
                                   (__attribute__((address_space(3))) void*)l, 16, 0, 0);
}

__device__ __forceinline__ void gemm_tiles(const u16* __restrict__ A, const u16* __restrict__ Bw,
                                           int K, int m0, int n0, u16* Ash, u16* Bsh,
                                           f32x4 acc[4][4]) {
  const int tid = threadIdx.x;
  const int lane = tid & 63;
  const int w = tid >> 6;
  const int wr = (w >> 1) * 64, wc = (w & 1) * 64;
  const int lr = lane & 15;
  const int lkb = (lane >> 4) << 3;
  const int r0 = tid >> 2;         // 0..63
  const int c0 = (tid & 3) << 3;   // 0,8,16,24

  for (int k0 = 0; k0 < K; k0 += 32) {
#pragma unroll
    for (int s = 0; s < 2; s++) {
      gload_lds16(&A[(size_t)(m0 + s * 64 + r0) * K + k0 + c0], &Ash[(s * 256 + tid) * 8]);
      gload_lds16(&Bw[(size_t)(n0 + s * 64 + r0) * K + k0 + c0], &Bsh[(s * 256 + tid) * 8]);
    }
    __syncthreads();
    Frag af[4], bfr[4];
#pragma unroll
    for (int i = 0; i < 4; i++) {
      af[i].i4 = *(const int4*)&Ash[(wr + i * 16 + lr) * 32 + lkb];
      bfr[i].i4 = *(const int4*)&Bsh[(wc + i * 16 + lr) * 32 + lkb];
    }
#pragma unroll
    for (int mf = 0; mf < 4; mf++)
#pragma unroll
      for (int nf = 0; nf < 4; nf++)
        acc[mf][nf] = __builtin_amdgcn_mfma_f32_16x16x32_bf16(af[mf].b, bfr[nf].b, acc[mf][nf], 0, 0, 0);
    __syncthreads();
  }
}

// ---------------- GEMM1: kqv = x @ Wkqv^T + b ----------------
// q/k scattered to [bh][t][d]; v^T to [bh][d][c] where c = t with BITS 2<->3 of
// (t&63) swapped — attention's P-register kv order matches this permutation.
__global__ __launch_bounds__(256) void gemm_kqv(const u16* __restrict__ xb, const u16* __restrict__ wb,
                                                const float* __restrict__ bias,
                                                u16* __restrict__ qb, u16* __restrict__ kb,
                                                u16* __restrict__ vtb) {
  __shared__ u16 Ash[128 * 32];
  __shared__ u16 Bsh[128 * 32];
  const int m0 = blockIdx.y * 128, n0 = blockIdx.x * 128;
  f32x4 acc[4][4];
#pragma unroll
  for (int i = 0; i < 4; i++)
#pragma unroll
    for (int j = 0; j < 4; j++) acc[i][j] = (f32x4){0.f, 0.f, 0.f, 0.f};

  gemm_tiles(xb, wb, CDIM, m0, n0, Ash, Bsh, acc);

  const int tid = threadIdx.x;
  const int lane = tid & 63;
  const int w = tid >> 6;
  const int wr = (w >> 1) * 64, wc = (w & 1) * 64;
  const int lr = lane & 15;
  const int rbase = (lane >> 4) << 2;
#pragma unroll
  for (int mf = 0; mf < 4; mf++) {
#pragma unroll
    for (int nf = 0; nf < 4; nf++) {
      f32x4 a = acc[mf][nf];
      int n = n0 + wc + nf * 16 + lr;
      float bval = bias[n];
      int h = n / 192;
      int rem = n - h * 192;
      int s = rem >> 6;
      int d = rem & 63;
      float scale = (s == 1) ? 0.125f : 1.f;  // fold 1/sqrt(64) into q
      u16* dst = (s == 0) ? kb : qb;
#pragma unroll
      for (int r = 0; r < 4; r++) {
        int m = m0 + wr + mf * 16 + rbase + r;
        int bb = m >> 11, tt = m & 2047;
        int bh = (bb << 4) + h;
        u16 val = f2b((a[r] + bval) * scale);
        if (s == 2) {
          int t63 = tt & 63;
          int c = (t63 & 51) | ((t63 & 8) >> 1) | ((t63 & 4) << 1);  // swap bits 2,3
          vtb[((size_t)bh * HD + d) * TSEQ + (tt & ~63) + c] = val;
        } else {
          dst[((size_t)bh * TSEQ + tt) * HD + d] = val;
        }
      }
    }
  }
}

// ---------------- GEMM2: out = y @ Wproj^T + b (fp32 out) ----------------
__global__ __launch_bounds__(256) void gemm_proj(const u16* __restrict__ yb, const u16* __restrict__ wb,
                                                 const float* __restrict__ bias,
                                                 float* __restrict__ out) {
  __shared__ u16 Ash[128 * 32];
  __shared__ u16 Bsh[128 * 32];
  const int m0 = blockIdx.y * 128, n0 = blockIdx.x * 128;
  f32x4 acc[4][4];
#pragma unroll
  for (int i = 0; i < 4; i++)
#pragma unroll
    for (int j = 0; j < 4; j++) acc[i][j] = (f32x4){0.f, 0.f, 0.f, 0.f};

  gemm_tiles(yb, wb, CDIM, m0, n0, Ash, Bsh, acc);

  const int tid = threadIdx.x;
  const int lane = tid & 63;
  const int w = tid >> 6;
  const int wr = (w >> 1) * 64, wc = (w & 1) * 64;
  const int lr = lane & 15;
  const int rbase = (lane >> 4) << 2;
#pragma unroll
  for (int mf = 0; mf < 4; mf++) {
#pragma unroll
    for (int nf = 0; nf < 4; nf++) {
      f32x4 a = acc[mf][nf];
      int n = n0 + wc + nf * 16 + lr;
      float bval = bias[n];
#pragma unroll
      for (int r = 0; r < 4; r++) {
        int m = m0 + wr + mf * 16 + rbase + r;
        out[(size_t)m * CDIM + n] = a[r] + bval;
      }
    }
  }
}

// ---------------- causal flash attention v10: coalesced LDS staging, register P ----
// 512 blocks x 256 threads (4 waves x 32 q-rows, QBLK=128). Every global access is
// coalesced: K and V tiles (64x64) staged via global_load_lds (16B/lane contiguous,
// XOR-pre-swizzled source), double-buffered; fragments via conflict-free swizzled
// ds_read_b128. r7-r9's direct loads were 32-line GATHERS (128B lane stride) that
// serialized the per-CU TA pipe — that was the invariant ~60-70us wall.
// Iteration order: barrier -> ds_read all frags -> STAGE next tile -> register-only
// math. No ds_read follows the stage, so the compiler cannot serialize stage vs
// compute with a conservative vmcnt(0); the stage drains at the NEXT barrier
// (= overlaps the whole math phase).
// Register-P swapped softmax (r8, proven): S^T = K.Q^T, fixed-shift exp, cvt_pk
// pack in the lane's own kv order matching the bit2<->3-permuted V^T layout.
// Balance: classes (15-c, c) paired -> every CU's 2 blocks sum to exactly 34 tiles.
__global__ __launch_bounds__(256, 2) void attn_kernel(const u16* __restrict__ qb,
                                                      const u16* __restrict__ kb,
                                                      const u16* __restrict__ vtb,
                                                      u16* __restrict__ yb) {
  __shared__ u16 Ksh[2][64 * 64];
  __shared__ u16 Vsh[2][64 * 64];

  const int tid = threadIdx.x;
  const int lane = tid & 63;
  const int w = tid >> 6;          // 0..3
  const int l31 = lane & 31;
  const int hi32 = lane >> 5;
  const int swz = l31 & 7;

  const int jj = blockIdx.x;
  const int bh = jj & 31;
  const int cls = jj >> 5;                      // 0..15
  const int qbk = (cls < 8) ? (15 - cls) : (cls - 8);  // heavy first; pair sums = 34 tiles
  const int q0w = qbk * 128 + w * 32;
  const int LN = 2 * qbk + 2;
  const int jd = q0w >> 6;                      // this wave's diagonal tile
  const int qg = q0w + l31;

  const u16* Qp = qb + (size_t)bh * TSEQ * HD;
  const u16* Kp = kb + (size_t)bh * TSEQ * HD;
  const u16* Vt = vtb + (size_t)bh * HD * TSEQ;

  // Q B-frags (4 d-steps of 16) in registers for the whole job
  Frag qf[4];
#pragma unroll
  for (int k = 0; k < 4; k++)
    qf[k].i4 = *(const int4*)&Qp[(size_t)(q0w + l31) * HD + k * 16 + hi32 * 8];

  f32x16 O0, O1;
  float lp = 0.f;
#pragma unroll
  for (int i = 0; i < 16; i++) { O0[i] = 0.f; O1[i] = 0.f; }

  // staging: 512 16B-chunks per 64x64 tile, 2 per thread; LDS dest linear
  // (wave-uniform base + lane*16), source pre-swizzled so swizzled reads are
  // conflict-free.
#define STAGE(B, JT)                                                                 \
  {                                                                                  \
    const int kvb = (JT) * 64;                                                       \
    _Pragma("unroll") for (int p = 0; p < 2; p++) {                                  \
      int c = tid + p * 256;                                                         \
      int row = c >> 3, c16 = c & 7;                                                 \
      int gofs = (c16 ^ (row & 7)) << 3;                                             \
      gload_lds16(&Kp[(size_t)(kvb + row) * HD + gofs], &Ksh[B][c * 8]);             \
      gload_lds16(&Vt[(size_t)row * TSEQ + kvb + gofs], &Vsh[B][c * 8]);             \
    }                                                                                \
  }

#define PACK2(dst, SV, base)                                                         \
    asm("v_cvt_pk_bf16_f32 %0, %1, %2" : "=v"(dst.i4.x) : "v"(SV[base + 0]), "v"(SV[base + 1])); \
    asm("v_cvt_pk_bf16_f32 %0, %1, %2" : "=v"(dst.i4.y) : "v"(SV[base + 2]), "v"(SV[base + 3])); \
    asm("v_cvt_pk_bf16_f32 %0, %1, %2" : "=v"(dst.i4.z) : "v"(SV[base + 4]), "v"(SV[base + 5])); \
    asm("v_cvt_pk_bf16_f32 %0, %1, %2" : "=v"(dst.i4.w) : "v"(SV[base + 6]), "v"(SV[base + 7]));

  STAGE(0, 0)
  int cur = 0;
  for (int jt = 0; jt < LN; ++jt) {
    __syncthreads();  // buf[cur] staged (barrier's vmcnt(0) drains prev STAGE)
    const int kv0 = jt * 64;
    const bool act = (jt <= jd);                    // wave-uniform
    const bool run1 = (kv0 + 32) <= (q0w + 31);     // wave-uniform (2nd kv half live)

    // ---- phase 1: all LDS->reg fragment reads (before STAGE; no ds_read after) ----
    Frag ka0[4], ka1[4], vf0[4], vf1[4];
    if (act) {
      const u16* Kt = Ksh[cur];
      const u16* Vl = Vsh[cur];
#pragma unroll
      for (int k = 0; k < 4; k++) {
        int ch = ((2 * k + hi32) ^ swz) << 3;
        ka0[k].i4 = *(const int4*)&Kt[l31 * 64 + ch];
        vf0[k].i4 = *(const int4*)&Vl[l31 * 64 + ch];
        vf1[k].i4 = *(const int4*)&Vl[(32 + l31) * 64 + ch];
      }
      if (run1) {
#pragma unroll
        for (int k = 0; k < 4; k++) {
          int ch = ((2 * k + hi32) ^ swz) << 3;
          ka1[k].i4 = *(const int4*)&Kt[(32 + l31) * 64 + ch];
        }
      }
    }
    __builtin_amdgcn_sched_barrier(0);
    // ---- phase 2: issue next tile's staging (drains at NEXT barrier) ----
    if (jt + 1 < LN) STAGE(cur ^ 1, jt + 1)
    __builtin_amdgcn_sched_barrier(0);
    // ---- phase 3: register-only math ----
    if (act) {
      const bool diag = (jt == jd);
      // kv half 0
      f32x16 S;
#pragma unroll
      for (int i = 0; i < 16; i++) S[i] = 0.f;
      __builtin_amdgcn_s_setprio(1);
#pragma unroll
      for (int k = 0; k < 4; k++)
        S = __builtin_amdgcn_mfma_f32_32x32x16_bf16(ka0[k].b, qf[k].b, S, 0, 0, 0);
      __builtin_amdgcn_s_setprio(0);
      if (diag) {
#pragma unroll
        for (int reg = 0; reg < 16; reg++) {
          int crow = (reg & 3) + 8 * (reg >> 2) + 4 * hi32;
          S[reg] = (kv0 + crow <= qg) ? __expf(S[reg]) : 0.f;
        }
      } else {
#pragma unroll
        for (int reg = 0; reg < 16; reg++) S[reg] = __expf(S[reg]);
      }
#pragma unroll
      for (int reg = 0; reg < 16; reg++) lp += S[reg];
      Frag pa[2];
      PACK2(pa[0], S, 0)
      PACK2(pa[1], S, 8)
      __builtin_amdgcn_s_setprio(1);
#pragma unroll
      for (int k = 0; k < 2; k++) {
        O0 = __builtin_amdgcn_mfma_f32_32x32x16_bf16(pa[k].b, vf0[k].b, O0, 0, 0, 0);
        O1 = __builtin_amdgcn_mfma_f32_32x32x16_bf16(pa[k].b, vf1[k].b, O1, 0, 0, 0);
      }
      __builtin_amdgcn_s_setprio(0);
      // kv half 1
      if (run1) {
        f32x16 T;
#pragma unroll
        for (int i = 0; i < 16; i++) T[i] = 0.f;
        __builtin_amdgcn_s_setprio(1);
#pragma unroll
        for (int k = 0; k < 4; k++)
          T = __builtin_amdgcn_mfma_f32_32x32x16_bf16(ka1[k].b, qf[k].b, T, 0, 0, 0);
        __builtin_amdgcn_s_setprio(0);
        if (diag) {
#pragma unroll
          for (int reg = 0; reg < 16; reg++) {
            int crow = (reg & 3) + 8 * (reg >> 2) + 4 * hi32;
            T[reg] = (kv0 + 32 + crow <= qg) ? __expf(T[reg]) : 0.f;
          }
        } else {
#pragma unroll
          for (int reg = 0; reg < 16; reg++) T[reg] = __expf(T[reg]);
        }
#pragma unroll
        for (int reg = 0; reg < 16; reg++) lp += T[reg];
        Frag pb[2];
        PACK2(pb[0], T, 0)
        PACK2(pb[1], T, 8)
        __builtin_amdgcn_s_setprio(1);
#pragma unroll
        for (int k = 0; k < 2; k++) {
          O0 = __builtin_amdgcn_mfma_f32_32x32x16_bf16(pb[k].b, vf0[k + 2].b, O0, 0, 0, 0);
          O1 = __builtin_amdgcn_mfma_f32_32x32x16_bf16(pb[k].b, vf1[k + 2].b, O1, 0, 0, 0);
        }
        __builtin_amdgcn_s_setprio(0);
      }
    }
    cur ^= 1;
  }
#undef STAGE
#undef PACK2

  // row sums: lane^32 partner holds the other half of the same q row's partials
  float lpt = lp + __shfl_xor(lp, 32);
  const int b = bh >> 4, h = bh & 15;
#pragma unroll
  for (int reg = 0; reg < 16; reg++) {
    int qlocal = (reg & 3) + 8 * (reg >> 2) + 4 * hi32;
    float invr = 1.f / __shfl(lpt, qlocal);
    int t = q0w + qlocal;
    size_t rowoff = ((size_t)(b * TSEQ + t) << 10) + (h << 6);
    yb[rowoff + l31] = f2b(O0[reg] * invr);
    yb[rowoff + 32 + l31] = f2b(O1[reg] * invr);
  }
}

extern "C" void kernel_launch(void* const* d_in, const int* in_sizes, int n_in,
                              void* d_out, int out_size, void* d_ws, size_t ws_size,
                              hipStream_t stream) {
  const float* x = (const float*)d_in[0];
  const float* Wkqv = (const float*)d_in[1];
  const float* bkqv = (const float*)d_in[2];
  const float* Wproj = (const float*)d_in[3];
  const float* bproj = (const float*)d_in[4];
  float* out = (float*)d_out;

  u16* ws = (u16*)d_ws;
  u16* xb = ws;                       // 4194304
  u16* wkqvb = xb + 4194304;          // 3145728
  u16* wprojb = wkqvb + 3145728;      // 1048576
  u16* qb = wprojb + 1048576;         // 4194304
  u16* kb = qb + 4194304;             // 4194304
  u16* vtb = kb + 4194304;            // 4194304 ([bh][d][t], cols bit-2/3 swapped per 64)
  u16* yb = vtb + 4194304;            // 4194304  (total 48 MB)

  cvt3_kernel<<<2048, 256, 0, stream>>>(x, Wkqv, Wproj, xb, wkqvb, wprojb);
  gemm_kqv<<<dim3(24, 32), 256, 0, stream>>>(xb, wkqvb, bkqv, qb, kb, vtb);
  attn_kernel<<<512, 256, 0, stream>>>(qb, kb, vtb, yb);
  gemm_proj<<<dim3(8, 32), 256, 0, stream>>>(yb, wprojb, bproj, out);
}

// Round 11
// 98.068 us; speedup vs baseline: 1.4424x; 1.1104x over previous
//
#include <hip/hip_runtime.h>

#define TSEQ 2048
#define NHEAD 16
#define HD 64
#define CDIM 1024
#define BT 4096  // B*T

typedef unsigned short u16;
typedef __bf16 bf16x8 __attribute__((ext_vector_type(8)));
typedef float f32x4 __attribute__((ext_vector_type(4)));
typedef float f32x16 __attribute__((ext_vector_type(16)));

union Frag {
  int4 i4;
  bf16x8 b;
  u16 u[8];
};

__device__ __forceinline__ u16 f2b(float f) {
  union { float f; unsigned u; } x;
  x.f = f;
  unsigned r = x.u + 0x7fffu + ((x.u >> 16) & 1u);
  return (u16)(r >> 16);
}

// ---------------- fp32 -> bf16 convert (all three inputs, one launch) ----------------
#define N4X 1048576   // x: 4194304 f32
#define N4W1 786432   // Wkqv: 3145728
#define N4W2 262144   // Wproj: 1048576
__global__ void cvt3_kernel(const float* __restrict__ x, const float* __restrict__ w1,
                            const float* __restrict__ w2, u16* __restrict__ ox,
                            u16* __restrict__ o1, u16* __restrict__ o2) {
  int i = blockIdx.x * blockDim.x + threadIdx.x;
  int stride = gridDim.x * blockDim.x;
  for (int idx = i; idx < N4X + N4W1 + N4W2; idx += stride) {
    const float4* src;
    ushort4* dst;
    int k;
    if (idx < N4X) { src = (const float4*)x; dst = (ushort4*)ox; k = idx; }
    else if (idx < N4X + N4W1) { src = (const float4*)w1; dst = (ushort4*)o1; k = idx - N4X; }
    else { src = (const float4*)w2; dst = (ushort4*)o2; k = idx - N4X - N4W1; }
    float4 f = src[k];
    ushort4 o;
    o.x = f2b(f.x); o.y = f2b(f.y); o.z = f2b(f.z); o.w = f2b(f.w);
    dst[k] = o;
  }
}

// ---------------- shared GEMM mainloop (C = A * Bw^T), 128x128 tile ----------------
// v11: double-buffered LDS, ONE barrier per K-step, phase order
// barrier -> ds_read frags -> STAGE(next) -> MFMA (stage drains at NEXT barrier,
// overlapping the math phase — the r10 attention lesson applied to the GEMMs).
// LDS XOR-swizzle both-sides (pre-swizzled global source + swizzled ds_read):
// chunk ^= (row>>1)&3 — kills the 8-way conflict of 64B rows (3.1e6 -> ~0).
__device__ __forceinline__ void gload_lds16(const u16* g, u16* l) {
  __builtin_amdgcn_global_load_lds((__attribute__((address_space(1))) void*)g,
                                   (__attribute__((address_space(3))) void*)l, 16, 0, 0);
}

__device__ __forceinline__ void gemm_tiles(const u16* __restrict__ A, const u16* __restrict__ Bw,
                                           int K, int m0, int n0,
                                           u16 (*__restrict__ Ash)[128 * 32],
                                           u16 (*__restrict__ Bsh)[128 * 32],
                                           f32x4 acc[4][4]) {
  const int tid = threadIdx.x;
  const int lane = tid & 63;
  const int w = tid >> 6;
  const int wr = (w >> 1) * 64, wc = (w & 1) * 64;
  const int lr = lane & 15;
  const int hi = lane >> 4;
  const int r0 = tid >> 2;                       // 0..63 (staging row within half)
  const int cS = ((tid & 3) ^ ((tid >> 3) & 3)) << 3;  // pre-swizzled source col (u16)
  const int frg = (hi ^ ((lr >> 1) & 3)) << 3;   // swizzled frag chunk (u16)

#define GSTAGE(B, KO)                                                                 \
  { _Pragma("unroll") for (int s = 0; s < 2; s++) {                                   \
      gload_lds16(&A[(size_t)(m0 + s * 64 + r0) * K + (KO) + cS], &Ash[B][(s * 256 + tid) * 8]); \
      gload_lds16(&Bw[(size_t)(n0 + s * 64 + r0) * K + (KO) + cS], &Bsh[B][(s * 256 + tid) * 8]); \
  } }

  GSTAGE(0, 0)
  int cur = 0;
  for (int k0 = 0; k0 < K; k0 += 32) {
    __syncthreads();  // buf[cur] staged (prev STAGE drains here, overlapped with prev math)
    Frag af[4], bfr[4];
#pragma unroll
    for (int i = 0; i < 4; i++) {
      af[i].i4 = *(const int4*)&Ash[cur][(wr + i * 16 + lr) * 32 + frg];
      bfr[i].i4 = *(const int4*)&Bsh[cur][(wc + i * 16 + lr) * 32 + frg];
    }
    __builtin_amdgcn_sched_barrier(0);
    if (k0 + 32 < K) GSTAGE(cur ^ 1, k0 + 32)
    __builtin_amdgcn_sched_barrier(0);
#pragma unroll
    for (int mf = 0; mf < 4; mf++)
#pragma unroll
      for (int nf = 0; nf < 4; nf++)
        acc[mf][nf] = __builtin_amdgcn_mfma_f32_16x16x32_bf16(af[mf].b, bfr[nf].b, acc[mf][nf], 0, 0, 0);
    cur ^= 1;
  }
#undef GSTAGE
}

// ---------------- GEMM1: kqv = x @ Wkqv^T + b ----------------
// q/k scattered to [bh][t][d]; v^T to [bh][d][c] where c = t with BITS 2<->3 of
// (t&63) swapped — attention's P-register kv order matches this permutation.
__global__ __launch_bounds__(256) void gemm_kqv(const u16* __restrict__ xb, const u16* __restrict__ wb,
                                                const float* __restrict__ bias,
                                                u16* __restrict__ qb, u16* __restrict__ kb,
                                                u16* __restrict__ vtb) {
  __shared__ u16 Ash[2][128 * 32];
  __shared__ u16 Bsh[2][128 * 32];
  const int m0 = blockIdx.y * 128, n0 = blockIdx.x * 128;
  f32x4 acc[4][4];
#pragma unroll
  for (int i = 0; i < 4; i++)
#pragma unroll
    for (int j = 0; j < 4; j++) acc[i][j] = (f32x4){0.f, 0.f, 0.f, 0.f};

  gemm_tiles(xb, wb, CDIM, m0, n0, Ash, Bsh, acc);

  const int tid = threadIdx.x;
  const int lane = tid & 63;
  const int w = tid >> 6;
  const int wr = (w >> 1) * 64, wc = (w & 1) * 64;
  const int lr = lane & 15;
  const int rbase = (lane >> 4) << 2;
#pragma unroll
  for (int mf = 0; mf < 4; mf++) {
#pragma unroll
    for (int nf = 0; nf < 4; nf++) {
      f32x4 a = acc[mf][nf];
      int n = n0 + wc + nf * 16 + lr;
      float bval = bias[n];
      int h = n / 192;
      int rem = n - h * 192;
      int s = rem >> 6;
      int d = rem & 63;
      int m00 = m0 + wr + mf * 16 + rbase;       // r=0 row (bits 0-1 zero)
      int bb = m00 >> 11, tt = m00 & 2047;
      int bh = (bb << 4) + h;
      if (s == 2) {
        // 4 consecutive t -> 4 consecutive permuted cols (swap touches bits 2,3 only)
        int t63 = tt & 63;
        int c = (t63 & 51) | ((t63 & 8) >> 1) | ((t63 & 4) << 1);
        ushort4 v4;
        v4.x = f2b(a[0] + bval); v4.y = f2b(a[1] + bval);
        v4.z = f2b(a[2] + bval); v4.w = f2b(a[3] + bval);
        *(ushort4*)&vtb[((size_t)bh * HD + d) * TSEQ + (tt & ~63) + c] = v4;
      } else {
        float scale = (s == 1) ? 0.125f : 1.f;   // fold 1/sqrt(64) into q
        u16* dst = (s == 0) ? kb : qb;
#pragma unroll
        for (int r = 0; r < 4; r++)
          dst[((size_t)bh * TSEQ + tt + r) * HD + d] = f2b((a[r] + bval) * scale);
      }
    }
  }
}

// ---------------- GEMM2: out = y @ Wproj^T + b (fp32 out) ----------------
__global__ __launch_bounds__(256) void gemm_proj(const u16* __restrict__ yb, const u16* __restrict__ wb,
                                                 const float* __restrict__ bias,
                                                 float* __restrict__ out) {
  __shared__ u16 Ash[2][128 * 32];
  __shared__ u16 Bsh[2][128 * 32];
  const int m0 = blockIdx.y * 128, n0 = blockIdx.x * 128;
  f32x4 acc[4][4];
#pragma unroll
  for (int i = 0; i < 4; i++)
#pragma unroll
    for (int j = 0; j < 4; j++) acc[i][j] = (f32x4){0.f, 0.f, 0.f, 0.f};

  gemm_tiles(yb, wb, CDIM, m0, n0, Ash, Bsh, acc);

  const int tid = threadIdx.x;
  const int lane = tid & 63;
  const int w = tid >> 6;
  const int wr = (w >> 1) * 64, wc = (w & 1) * 64;
  const int lr = lane & 15;
  const int rbase = (lane >> 4) << 2;
#pragma unroll
  for (int mf = 0; mf < 4; mf++) {
#pragma unroll
    for (int nf = 0; nf < 4; nf++) {
      f32x4 a = acc[mf][nf];
      int n = n0 + wc + nf * 16 + lr;
      float bval = bias[n];
#pragma unroll
      for (int r = 0; r < 4; r++) {
        int m = m0 + wr + mf * 16 + rbase + r;
        out[(size_t)m * CDIM + n] = a[r] + bval;
      }
    }
  }
}

// ---------------- causal flash attention v10 (unchanged from round 10) ----------------
__global__ __launch_bounds__(256, 2) void attn_kernel(const u16* __restrict__ qb,
                                                      const u16* __restrict__ kb,
                                                      const u16* __restrict__ vtb,
                                                      u16* __restrict__ yb) {
  __shared__ u16 Ksh[2][64 * 64];
  __shared__ u16 Vsh[2][64 * 64];

  const int tid = threadIdx.x;
  const int lane = tid & 63;
  const int w = tid >> 6;          // 0..3
  const int l31 = lane & 31;
  const int hi32 = lane >> 5;
  const int swz = l31 & 7;

  const int jj = blockIdx.x;
  const int bh = jj & 31;
  const int cls = jj >> 5;                      // 0..15
  const int qbk = (cls < 8) ? (15 - cls) : (cls - 8);  // heavy first; pair sums = 34 tiles
  const int q0w = qbk * 128 + w * 32;
  const int LN = 2 * qbk + 2;
  const int jd = q0w >> 6;                      // this wave's diagonal tile
  const int qg = q0w + l31;

  const u16* Qp = qb + (size_t)bh * TSEQ * HD;
  const u16* Kp = kb + (size_t)bh * TSEQ * HD;
  const u16* Vt = vtb + (size_t)bh * HD * TSEQ;

  Frag qf[4];
#pragma unroll
  for (int k = 0; k < 4; k++)
    qf[k].i4 = *(const int4*)&Qp[(size_t)(q0w + l31) * HD + k * 16 + hi32 * 8];

  f32x16 O0, O1;
  float lp = 0.f;
#pragma unroll
  for (int i = 0; i < 16; i++) { O0[i] = 0.f; O1[i] = 0.f; }

#define STAGE(B, JT)                                                                 \
  {                                                                                  \
    const int kvb = (JT) * 64;                                                       \
    _Pragma("unroll") for (int p = 0; p < 2; p++) {                                  \
      int c = tid + p * 256;                                                         \
      int row = c >> 3, c16 = c & 7;                                                 \
      int gofs = (c16 ^ (row & 7)) << 3;                                             \
      gload_lds16(&Kp[(size_t)(kvb + row) * HD + gofs], &Ksh[B][c * 8]);             \
      gload_lds16(&Vt[(size_t)row * TSEQ + kvb + gofs], &Vsh[B][c * 8]);             \
    }                                                                                \
  }

#define PACK2(dst, SV, base)                                                         \
    asm("v_cvt_pk_bf16_f32 %0, %1, %2" : "=v"(dst.i4.x) : "v"(SV[base + 0]), "v"(SV[base + 1])); \
    asm("v_cvt_pk_bf16_f32 %0, %1, %2" : "=v"(dst.i4.y) : "v"(SV[base + 2]), "v"(SV[base + 3])); \
    asm("v_cvt_pk_bf16_f32 %0, %1, %2" : "=v"(dst.i4.z) : "v"(SV[base + 4]), "v"(SV[base + 5])); \
    asm("v_cvt_pk_bf16_f32 %0, %1, %2" : "=v"(dst.i4.w) : "v"(SV[base + 6]), "v"(SV[base + 7]));

  STAGE(0, 0)
  int cur = 0;
  for (int jt = 0; jt < LN; ++jt) {
    __syncthreads();
    const int kv0 = jt * 64;
    const bool act = (jt <= jd);
    const bool run1 = (kv0 + 32) <= (q0w + 31);

    Frag ka0[4], ka1[4], vf0[4], vf1[4];
    if (act) {
      const u16* Kt = Ksh[cur];
      const u16* Vl = Vsh[cur];
#pragma unroll
      for (int k = 0; k < 4; k++) {
        int ch = ((2 * k + hi32) ^ swz) << 3;
        ka0[k].i4 = *(const int4*)&Kt[l31 * 64 + ch];
        vf0[k].i4 = *(const int4*)&Vl[l31 * 64 + ch];
        vf1[k].i4 = *(const int4*)&Vl[(32 + l31) * 64 + ch];
      }
      if (run1) {
#pragma unroll
        for (int k = 0; k < 4; k++) {
          int ch = ((2 * k + hi32) ^ swz) << 3;
          ka1[k].i4 = *(const int4*)&Kt[(32 + l31) * 64 + ch];
        }
      }
    }
    __builtin_amdgcn_sched_barrier(0);
    if (jt + 1 < LN) STAGE(cur ^ 1, jt + 1)
    __builtin_amdgcn_sched_barrier(0);
    if (act) {
      const bool diag = (jt == jd);
      f32x16 S;
#pragma unroll
      for (int i = 0; i < 16; i++) S[i] = 0.f;
      __builtin_amdgcn_s_setprio(1);
#pragma unroll
      for (int k = 0; k < 4; k++)
        S = __builtin_amdgcn_mfma_f32_32x32x16_bf16(ka0[k].b, qf[k].b, S, 0, 0, 0);
      __builtin_amdgcn_s_setprio(0);
      if (diag) {
#pragma unroll
        for (int reg = 0; reg < 16; reg++) {
          int crow = (reg & 3) + 8 * (reg >> 2) + 4 * hi32;
          S[reg] = (kv0 + crow <= qg) ? __expf(S[reg]) : 0.f;
        }
      } else {
#pragma unroll
        for (int reg = 0; reg < 16; reg++) S[reg] = __expf(S[reg]);
      }
#pragma unroll
      for (int reg = 0; reg < 16; reg++) lp += S[reg];
      Frag pa[2];
      PACK2(pa[0], S, 0)
      PACK2(pa[1], S, 8)
      __builtin_amdgcn_s_setprio(1);
#pragma unroll
      for (int k = 0; k < 2; k++) {
        O0 = __builtin_amdgcn_mfma_f32_32x32x16_bf16(pa[k].b, vf0[k].b, O0, 0, 0, 0);
        O1 = __builtin_amdgcn_mfma_f32_32x32x16_bf16(pa[k].b, vf1[k].b, O1, 0, 0, 0);
      }
      __builtin_amdgcn_s_setprio(0);
      if (run1) {
        f32x16 T;
#pragma unroll
        for (int i = 0; i < 16; i++) T[i] = 0.f;
        __builtin_amdgcn_s_setprio(1);
#pragma unroll
        for (int k = 0; k < 4; k++)
          T = __builtin_amdgcn_mfma_f32_32x32x16_bf16(ka1[k].b, qf[k].b, T, 0, 0, 0);
        __builtin_amdgcn_s_setprio(0);
        if (diag) {
#pragma unroll
          for (int reg = 0; reg < 16; reg++) {
            int crow = (reg & 3) + 8 * (reg >> 2) + 4 * hi32;
            T[reg] = (kv0 + 32 + crow <= qg) ? __expf(T[reg]) : 0.f;
          }
        } else {
#pragma unroll
          for (int reg = 0; reg < 16; reg++) T[reg] = __expf(T[reg]);
        }
#pragma unroll
        for (int reg = 0; reg < 16; reg++) lp += T[reg];
        Frag pb[2];
        PACK2(pb[0], T, 0)
        PACK2(pb[1], T, 8)
        __builtin_amdgcn_s_setprio(1);
#pragma unroll
        for (int k = 0; k < 2; k++) {
          O0 = __builtin_amdgcn_mfma_f32_32x32x16_bf16(pb[k].b, vf0[k + 2].b, O0, 0, 0, 0);
          O1 = __builtin_amdgcn_mfma_f32_32x32x16_bf16(pb[k].b, vf1[k + 2].b, O1, 0, 0, 0);
        }
        __builtin_amdgcn_s_setprio(0);
      }
    }
    cur ^= 1;
  }
#undef STAGE
#undef PACK2

  float lpt = lp + __shfl_xor(lp, 32);
  const int b = bh >> 4, h = bh & 15;
#pragma unroll
  for (int reg = 0; reg < 16; reg++) {
    int qlocal = (reg & 3) + 8 * (reg >> 2) + 4 * hi32;
    float invr = 1.f / __shfl(lpt, qlocal);
    int t = q0w + qlocal;
    size_t rowoff = ((size_t)(b * TSEQ + t) << 10) + (h << 6);
    yb[rowoff + l31] = f2b(O0[reg] * invr);
    yb[rowoff + 32 + l31] = f2b(O1[reg] * invr);
  }
}

extern "C" void kernel_launch(void* const* d_in, const int* in_sizes, int n_in,
                              void* d_out, int out_size, void* d_ws, size_t ws_size,
                              hipStream_t stream) {
  const float* x = (const float*)d_in[0];
  const float* Wkqv = (const float*)d_in[1];
  const float* bkqv = (const float*)d_in[2];
  const float* Wproj = (const float*)d_in[3];
  const float* bproj = (const float*)d_in[4];
  float* out = (float*)d_out;

  u16* ws = (u16*)d_ws;
  u16* xb = ws;                       // 4194304
  u16* wkqvb = xb + 4194304;          // 3145728
  u16* wprojb = wkqvb + 3145728;      // 1048576
  u16* qb = wprojb + 1048576;         // 4194304
  u16* kb = qb + 4194304;             // 4194304
  u16* vtb = kb + 4194304;            // 4194304 ([bh][d][t], cols bit-2/3 swapped per 64)
  u16* yb = vtb + 4194304;            // 4194304  (total 48 MB)

  cvt3_kernel<<<2048, 256, 0, stream>>>(x, Wkqv, Wproj, xb, wkqvb, wprojb);
  gemm_kqv<<<dim3(24, 32), 256, 0, stream>>>(xb, wkqvb, bkqv, qb, kb, vtb);
  attn_kernel<<<512, 256, 0, stream>>>(qb, kb, vtb, yb);
  gemm_proj<<<dim3(8, 32), 256, 0, stream>>>(yb, wprojb, bproj, out);
}